// Round 6
// baseline (249.171 us; speedup 1.0000x reference)
//
#include <hip/hip_runtime.h>
#include <hip/hip_fp16.h>

// CTC-like forward scan. R17 = R16 resubmit (infra failure, no counters).
//   G_t[p] = G_{t-1}[p] + W_t[p] * G_{t-1}[p-1],  W = exp(x_i - x_4)
// R15 evidence: VGPR_Count=64 < the 96 minimum for three live 8xu32x4 windows
// => the asm burst outputs went to alloca/scratch (lambda + array refs defeat
// SROA; rule #20), so ds_read latency was traded for scratch round-trips --
// no perf change (188us). The coalesced xq[b][t] layout cut FETCH 16.5->2.2MB
// with zero time delta (HBM never the limiter). Here every window register is
// an individually named u32x4 local, all control flow macro-expanded, no
// arrays touch the asm. 3-window rotation, ds_read_b128 bursts issued TWO
// windows ahead, lgkmcnt(8) waits (1-ahead burst stays in flight),
// sched_barrier(0) fences, 4-chunk-ahead global_load_lds staging.
// Validation bit: VGPR >= 110.
// Numerics identical to R14 (absmax 0.0): f16 weights via v_perm +
// v_fma_mix_f32, renorm every 8 steps, down-only alignment, boundary via one
// v_mov_dpp wave_shr:1, logs = sum x4 in f32.

#define TT 4096
#define BB 64
#define PP 512
#define LN2F 0.69314718055994531f

typedef unsigned u32x4 __attribute__((ext_vector_type(4)));

__device__ __forceinline__ unsigned f16_bits(float f) {
    return (unsigned)__half_as_ushort(__float2half(f));   // v_cvt_f16_f32, RNE
}

// prepass: x[t][b][5] -> xq[b*4096+t] = {f16W0|W1, f16W2|W3, f32 x4, 0}
__global__ __launch_bounds__(256, 1)
void ctc_prepass(const float* __restrict__ x, u32x4* __restrict__ xq) {
    int j = blockIdx.x * 256 + threadIdx.x;
    int b = j >> 12, t = j & 4095;
    const float* r = x + (size_t)(t * 64 + b) * 5;
    float x0 = r[0], x1 = r[1], x2 = r[2], x3 = r[3], x4 = r[4];
    float w0 = fminf(__expf(x0 - x4), 65000.0f);   // clamp: f16 inf insurance
    float w1 = fminf(__expf(x1 - x4), 65000.0f);
    float w2 = fminf(__expf(x2 - x4), 65000.0f);
    float w3 = fminf(__expf(x3 - x4), 65000.0f);
    u32x4 o;
    o[0] = f16_bits(w0) | (f16_bits(w1) << 16);
    o[1] = f16_bits(w2) | (f16_bits(w3) << 16);
    o[2] = __float_as_uint(x4);
    o[3] = 0u;
    xq[j] = o;
}

__device__ __forceinline__ void gload_lds16(const void* g, void* l) {
    auto gp = (const __attribute__((address_space(1))) void*)(uintptr_t)g;
    auto lp = (__attribute__((address_space(3))) void*)(uintptr_t)l;
    __builtin_amdgcn_global_load_lds(gp, lp, 16, 0, 0);
}

// lane n <- lane n-1 across the whole wave; lane 0 keeps old (overridden).
__device__ __forceinline__ int shl1w_i(int s) {
    return __builtin_amdgcn_update_dpp(s, s, 0x138 /*wave_shr:1*/, 0xF, 0xF, false);
}
__device__ __forceinline__ float shl1w_f(float s) {
    return __int_as_float(shl1w_i(__float_as_int(s)));
}

// 8x ds_read_b128 into 8 NAMED u32x4 registers (opaque to remat/SROA-proof).
#define BURST8(w0, w1, w2, w3, w4, w5, w6, w7, addr)                        \
    asm volatile(                                                           \
        "ds_read_b128 %0, %8 offset:0\n\t"                                  \
        "ds_read_b128 %1, %8 offset:16\n\t"                                 \
        "ds_read_b128 %2, %8 offset:32\n\t"                                 \
        "ds_read_b128 %3, %8 offset:48\n\t"                                 \
        "ds_read_b128 %4, %8 offset:64\n\t"                                 \
        "ds_read_b128 %5, %8 offset:80\n\t"                                 \
        "ds_read_b128 %6, %8 offset:96\n\t"                                 \
        "ds_read_b128 %7, %8 offset:112"                                    \
        : "=&v"(w0), "=&v"(w1), "=&v"(w2), "=&v"(w3),                       \
          "=&v"(w4), "=&v"(w5), "=&v"(w6), "=&v"(w7)                        \
        : "v"(addr))

// acc += s * f16(lo/hi of p)   -- one v_fma_mix_f32, f16 source in S1
#define FMA_MIX_LO(acc, s, p)                                              \
    asm("v_fma_mix_f32 %0, %1, %2, %0 op_sel:[0,0,0] op_sel_hi:[0,1,0]"    \
        : "+v"(acc) : "v"(s), "v"(p))
#define FMA_MIX_HI(acc, s, p)                                              \
    asm("v_fma_mix_f32 %0, %1, %2, %0 op_sel:[0,1,0] op_sel_hi:[0,1,0]"    \
        : "+v"(acc) : "v"(s), "v"(p))

// one time step from a resident row register
#define STEP(row)                                                          \
    do {                                                                   \
        logs += __uint_as_float((row)[2]);                                 \
        unsigned p0 = __builtin_amdgcn_perm((row)[1], (row)[0], ctrl0);    \
        unsigned p1 = __builtin_amdgcn_perm((row)[1], (row)[0], ctrl1);    \
        unsigned p2 = __builtin_amdgcn_perm((row)[1], (row)[0], ctrl2);    \
        unsigned p3 = __builtin_amdgcn_perm((row)[1], (row)[0], ctrl3);    \
        const float Flr = shl1w_f(F7);                                     \
        const float fin = fmaf(Flr, sAx, cfin);                            \
        FMA_MIX_HI(F7, F6, p3);                                            \
        FMA_MIX_LO(F6, F5, p3);                                            \
        FMA_MIX_HI(F5, F4, p2);                                            \
        FMA_MIX_LO(F4, F3, p2);                                            \
        FMA_MIX_HI(F3, F2, p1);                                            \
        FMA_MIX_LO(F2, F1, p1);                                            \
        FMA_MIX_HI(F1, F0, p0);                                            \
        FMA_MIX_LO(F0, fin, p0);                                           \
    } while (0)

// renorm every 8 steps + neighbor frame alignment (defines sAx, cfin)
#define BOOKKEEP()                                                         \
    float m = fmaxf(fmaxf(fmaxf(F0, F1), fmaxf(F2, F3)),                   \
                    fmaxf(fmaxf(F4, F5), fmaxf(F6, F7)));                  \
    int e2 = ((__float_as_int(m) >> 23) & 0xFF) - 127;                     \
    e2 = (m > 0.0f) ? e2 : 0;                                              \
    const int Mp = M + e2;                                                 \
    const int Mlp = shl1w_i(Mp);                                           \
    int dl = (lane0 ? 0 : Mlp) - Mp;                                       \
    int dlc = dl > 0 ? dl : 0;                                             \
    const int Mnew = Mp + dlc;                                             \
    const int sh = Mnew - M;                                               \
    F0 = ldexpf(F0, -sh); F1 = ldexpf(F1, -sh);                            \
    F2 = ldexpf(F2, -sh); F3 = ldexpf(F3, -sh);                            \
    F4 = ldexpf(F4, -sh); F5 = ldexpf(F5, -sh);                            \
    F6 = ldexpf(F6, -sh); F7 = ldexpf(F7, -sh);                            \
    M = Mnew;                                                              \
    int dn = Mlp - M; dn = dn > 0 ? 0 : dn;                                \
    const float sAx = lane0 ? 0.0f : ldexpf(1.0f, dn);                     \
    const float cfin = lane0 ? ldexpf(1.0f, -M) : 0.0f;

// one 8-step window: stage chunk (every 8th), wait cur resident (lgkmcnt(8)
// = oldest burst done, 1-ahead stays in flight), burst window i+2, compute.
#define WINDOW(i, C0, C1, C2, C3, C4, C5, C6, C7,                          \
                  N0, N1, N2, N3, N4, N5, N6, N7)                          \
    do {                                                                   \
        const int wi = (i);                                                \
        if ((wi & 7) == 0) {                                               \
            const int c = wi >> 3;                                         \
            if (c < 64) {                                                  \
                const int cs = (c + 4 > 63) ? 63 : (c + 4);                \
                gload_lds16(gsrc + cs * 64 + l,                            \
                            &ring[((c + 4) & 7) * 64 + l]);                \
                asm volatile("s_waitcnt vmcnt(3)" ::: "memory");           \
            }                                                              \
        }                                                                  \
        asm volatile("s_waitcnt lgkmcnt(8)" ::: "memory");                 \
        __builtin_amdgcn_sched_barrier(0);                                 \
        BURST8(N0, N1, N2, N3, N4, N5, N6, N7,                             \
               ring_base + (unsigned)((((wi + 2) * 8) & 511) * 16));       \
        __builtin_amdgcn_sched_barrier(0);                                 \
        if (wi < 512) {                                                    \
            BOOKKEEP();                                                    \
            STEP(C0); STEP(C1); STEP(C2); STEP(C3);                        \
            STEP(C4); STEP(C5); STEP(C6); STEP(C7);                        \
        }                                                                  \
    } while (0)

__global__ __launch_bounds__(64, 1)
void ctc_scan(const u32x4* __restrict__ xq, const int* __restrict__ seqs,
              const int* __restrict__ seqlens, float* __restrict__ out) {
    __shared__ __align__(16) u32x4 ring[512];      // 8 KB: 8 chunks x 64 rows
    __shared__ float garr[PP + 1];

    const int b = blockIdx.x;
    const int l = threadIdx.x;                     // 0..63
    const bool lane0 = (l == 0);

    // per-lane v_perm byte controls (value i at bytes 2i,2i+1 of {row[1]:row[0]})
    unsigned s0 = (unsigned)seqs[b * PP + 8 * l + 0];
    unsigned s1 = (unsigned)seqs[b * PP + 8 * l + 1];
    unsigned s2 = (unsigned)seqs[b * PP + 8 * l + 2];
    unsigned s3 = (unsigned)seqs[b * PP + 8 * l + 3];
    unsigned s4 = (unsigned)seqs[b * PP + 8 * l + 4];
    unsigned s5 = (unsigned)seqs[b * PP + 8 * l + 5];
    unsigned s6 = (unsigned)seqs[b * PP + 8 * l + 6];
    unsigned s7 = (unsigned)seqs[b * PP + 8 * l + 7];
    const unsigned ctrl0 = (2*s0) | ((2*s0+1)<<8) | ((2*s1)<<16) | ((2*s1+1)<<24);
    const unsigned ctrl1 = (2*s2) | ((2*s2+1)<<8) | ((2*s3)<<16) | ((2*s3+1)<<24);
    const unsigned ctrl2 = (2*s4) | ((2*s4+1)<<8) | ((2*s5)<<16) | ((2*s5+1)<<24);
    const unsigned ctrl3 = (2*s6) | ((2*s6+1)<<8) | ((2*s7)<<16) | ((2*s7+1)<<24);

    // column-major: row t of batch b at xq[b*4096 + t]; coalesced staging.
    const u32x4* gsrc = xq + (size_t)b * 4096;

    // ---- stage chunks 0..3 (64 rows each) ----
#pragma unroll
    for (int c0 = 0; c0 < 4; ++c0)
        gload_lds16(gsrc + c0 * 64 + l, &ring[c0 * 64 + l]);
    asm volatile("s_waitcnt vmcnt(3)" ::: "memory");   // chunk 0 resident

    const unsigned ring_base =
        (unsigned)(uintptr_t)(__attribute__((address_space(3))) void*)&ring[0];

    // ---- named window registers: 3 windows x 8 rows ----
    u32x4 X0, X1, X2, X3, X4, X5, X6, X7;
    u32x4 Y0, Y1, Y2, Y3, Y4, Y5, Y6, Y7;
    u32x4 Z0, Z1, Z2, Z3, Z4, Z5, Z6, Z7;

    // prologue: burst windows 0 (rows 0-7) and 1 (rows 8-15)
    BURST8(X0, X1, X2, X3, X4, X5, X6, X7, ring_base);
    BURST8(Y0, Y1, Y2, Y3, Y4, Y5, Y6, Y7, ring_base + 128);

    float F0 = 0.0f, F1 = 0.0f, F2 = 0.0f, F3 = 0.0f;
    float F4 = 0.0f, F5 = 0.0f, F6 = 0.0f, F7 = 0.0f;
    int M = 0;
    float logs = 0.0f;                             // sum of x_4

    // 513 windows (= 3*171): 512 active + 1 guard keeps rotation static.
#pragma unroll 1
    for (int i = 0; i < 513; i += 3) {
        WINDOW(i,     X0, X1, X2, X3, X4, X5, X6, X7,
                      Z0, Z1, Z2, Z3, Z4, Z5, Z6, Z7);
        WINDOW(i + 1, Y0, Y1, Y2, Y3, Y4, Y5, Y6, Y7,
                      X0, X1, X2, X3, X4, X5, X6, X7);
        WINDOW(i + 2, Z0, Z1, Z2, Z3, Z4, Z5, Z6, Z7,
                      Y0, Y1, Y2, Y3, Y4, Y5, Y6, Y7);
    }
    // drain in-flight bursts; pin all async-dest regs until after the drain
    asm volatile("s_waitcnt lgkmcnt(0)" ::: "memory");
    __builtin_amdgcn_sched_barrier(0);
    asm volatile("" ::
        "v"(X0), "v"(X1), "v"(X2), "v"(X3), "v"(X4), "v"(X5), "v"(X6), "v"(X7),
        "v"(Y0), "v"(Y1), "v"(Y2), "v"(Y3), "v"(Y4), "v"(Y5), "v"(Y6), "v"(Y7),
        "v"(Z0), "v"(Z1), "v"(Z2), "v"(Z3), "v"(Z4), "v"(Z5), "v"(Z6), "v"(Z7));

    // ---- epilogue: log2 reconstruction (denormal-safe) ----
    const float lgS = logs * 1.44269504088896341f;  // log2(prod S)
    float Fv[8] = {F0, F1, F2, F3, F4, F5, F6, F7};
#pragma unroll
    for (int i = 0; i < 8; ++i) {
        float v = fmaxf(Fv[i] * 16777216.0f, 1e-38f);
        garr[8 * l + 1 + i] = __log2f(v) - 24.0f + (float)M + lgS;
    }
    if (lane0) garr[0] = lgS;                       // position 0: log2(1) + lgS
    __syncthreads();
    if (lane0) {
        const int sl = seqlens[b];
        out[b] = -(garr[sl] * LN2F) / (float)TT;
    }
}

extern "C" void kernel_launch(void* const* d_in, const int* in_sizes, int n_in,
                              void* d_out, int out_size, void* d_ws, size_t ws_size,
                              hipStream_t stream) {
    const float* x       = (const float*)d_in[0];
    const int*   seqs    = (const int*)d_in[1];
    const int*   seqlens = (const int*)d_in[2];
    float*       out     = (float*)d_out;
    u32x4*       xq      = (u32x4*)d_ws;           // TT*BB rows x 16 B = 4 MB

    ctc_prepass<<<(TT * BB) / 256, 256, 0, stream>>>(x, xq);
    ctc_scan<<<BB, 64, 0, stream>>>(xq, seqs, seqlens, out);
}